// Round 5
// baseline (254.551 us; speedup 1.0000x reference)
//
#include <hip/hip_runtime.h>
#include <hip/hip_bf16.h>
#include <cstdint>

// ---------------------------------------------------------------------------
// B=2, S=4096, D=512, H=8, HD=64.
// wt: W -> W^T bf16.
// proj: QKV GEMM, 128x128 tiles, 16x16x32 bf16 MFMA (no launch-bounds cap ->
//       no spill; round-3's (256,2) bound spilled 128 acc VGPRs to scratch).
// attn: flash, S^T scheme, 32x32x16 MFMA, in-block K-split:
//   - block = 128 q x 2 K-halves; wave (wq,kh) owns 64 q x 2048 keys
//   - St = K·Q^T (keys in C-regs, q in lanes); softmax base-2, no max-sub
//   - V^T stored with key order permuted by sigma(key)=swap bits2,3 of key&15
//     => P's natural C-layout packing IS the PV B-operand fragment; the
//     cross-lane exchange (8 bpermute + 16 select) is deleted entirely.
//   - O/l of the two K-halves combined through LDS at the end.
// ---------------------------------------------------------------------------

typedef __bf16   bf16x8 __attribute__((ext_vector_type(8)));
typedef _Float16 f16x8  __attribute__((ext_vector_type(8)));
typedef float    f32x4  __attribute__((ext_vector_type(4)));
typedef float    f32x16 __attribute__((ext_vector_type(16)));
typedef unsigned int   u32;
typedef unsigned int   u32x4 __attribute__((ext_vector_type(4)));
typedef unsigned short u16;

#define NB  2
#define SEQ 4096
#define DIM 512
#define NH  8
#define HD  64
#define WSZ (DIM * DIM)
#define QSZ (NB * NH * SEQ * HD)

__device__ __forceinline__ u16 f2bf(float f) {
    __bf16 h = (__bf16)f; return __builtin_bit_cast(u16, h);
}
__device__ __forceinline__ u16 f2h(float f) {
    _Float16 h = (_Float16)f; return __builtin_bit_cast(u16, h);
}
__device__ __forceinline__ u32 pack_pkrtz(float a, float b) {
    auto pk = __builtin_amdgcn_cvt_pkrtz(a, b);   // __fp16 ext_vector_type(2)
    return __builtin_bit_cast(u32, pk);
}
__device__ __forceinline__ bf16x8 cvt8(const float* s) {
    float4 a = *(const float4*)s, b = *(const float4*)(s + 4);
    bf16x8 o;
    o[0]=(__bf16)a.x; o[1]=(__bf16)a.y; o[2]=(__bf16)a.z; o[3]=(__bf16)a.w;
    o[4]=(__bf16)b.x; o[5]=(__bf16)b.y; o[6]=(__bf16)b.z; o[7]=(__bf16)b.w;
    return o;
}

// --- W transpose: WT[p][n][k] = bf16(W_p[k][n]) -----------------------------
__global__ __launch_bounds__(256) void wt_kernel(
    const float* __restrict__ Wq, const float* __restrict__ Wk,
    const float* __restrict__ Wv, u16* __restrict__ wt)
{
    __shared__ u16 lT[64 * 65];
    const int p = blockIdx.z;
    const float* W = (p == 0) ? Wq : ((p == 1) ? Wk : Wv);
    u16* dst = wt + (size_t)p * WSZ;
    const int r0 = blockIdx.x * 64, c0 = blockIdx.y * 64;
    const int t = threadIdx.x;
#pragma unroll
    for (int i = 0; i < 16; i++) {
        int idx = i * 256 + t, row = idx >> 6, col = idx & 63;
        lT[col * 65 + row] = f2bf(W[(size_t)(r0 + row) * DIM + c0 + col]);
    }
    __syncthreads();
#pragma unroll
    for (int i = 0; i < 16; i++) {
        int idx = i * 256 + t, n = idx >> 6, k = idx & 63;
        dst[(size_t)(c0 + n) * DIM + r0 + k] = lT[n * 65 + k];
    }
}

// --- projection GEMM: 128x128 tiles ----------------------------------------
// p<2 : A = X rows (fp32,cvt), B = WT rows -> Q/K [B,H,S,64] bf16
// p==2: A = WT rows,    B = X rows (fp32,cvt) -> V^T [B,H,64,Sperm] f16
__global__ __launch_bounds__(256) void proj_kernel(
    const float* __restrict__ xq, const float* __restrict__ xk,
    const float* __restrict__ xv, const u16* __restrict__ wt,
    const float* __restrict__ bq, const float* __restrict__ bk,
    const float* __restrict__ bv,
    u16* __restrict__ qb, u16* __restrict__ kb, u16* __restrict__ vt)
{
    __shared__ u16 lA[128 * 72];
    __shared__ u16 lB[128 * 72];

    const int tid = threadIdx.x;
    const int wave = tid >> 6, lane = tid & 63;
    const int l16 = lane & 15, quad = lane >> 4;
    const int wq = wave >> 1, wn = wave & 1;

    int p, mb, nb;
    {
        const int id = blockIdx.x;
        if (id < 512) { p = id >> 8; const int r = id & 255; mb = r >> 2; nb = r & 3; }
        else          { p = 2; const int r = id - 512; mb = r >> 6; nb = r & 63; }
    }
    const float* Xp = (p == 0) ? xq : ((p == 1) ? xk : xv);
    const u16*   Wp = wt + (size_t)p * WSZ;
    const bool cvtA = (p < 2);
    const float* Af = Xp + (size_t)mb * 128 * DIM;   // if cvtA
    const u16*   Ab = Wp + (size_t)mb * 128 * DIM;   // if !cvtA
    const u16*   Bb = Wp + (size_t)nb * 128 * DIM;   // if cvtA
    const float* Bf = Xp + (size_t)nb * 128 * DIM;   // if !cvtA

    f32x4 acc[4][4];
#pragma unroll
    for (int ms = 0; ms < 4; ms++)
#pragma unroll
        for (int ns = 0; ns < 4; ns++)
#pragma unroll
            for (int j = 0; j < 4; j++) acc[ms][ns][j] = 0.f;

    for (int kk = 0; kk < DIM; kk += 64) {
        __syncthreads();
#pragma unroll
        for (int i = 0; i < 4; i++) {           // A: 128 rows x 8 segs
            const int c = i * 256 + tid, row = c >> 3, seg = c & 7;
            if (cvtA)
                *(bf16x8*)&lA[row * 72 + seg * 8] = cvt8(Af + (size_t)row * DIM + kk + seg * 8);
            else
                *(u32x4*)&lA[row * 72 + seg * 8] =
                    *(const u32x4*)(Ab + (size_t)row * DIM + kk + seg * 8);
        }
#pragma unroll
        for (int i = 0; i < 4; i++) {           // B: 128 rows x 8 segs
            const int c = i * 256 + tid, row = c >> 3, seg = c & 7;
            if (cvtA)
                *(u32x4*)&lB[row * 72 + seg * 8] =
                    *(const u32x4*)(Bb + (size_t)row * DIM + kk + seg * 8);
            else
                *(bf16x8*)&lB[row * 72 + seg * 8] = cvt8(Bf + (size_t)row * DIM + kk + seg * 8);
        }
        __syncthreads();

        bf16x8 af[4][2];
#pragma unroll
        for (int ms = 0; ms < 4; ms++) {
            af[ms][0] = *(const bf16x8*)&lA[(wq * 64 + ms * 16 + l16) * 72 + quad * 8];
            af[ms][1] = *(const bf16x8*)&lA[(wq * 64 + ms * 16 + l16) * 72 + 32 + quad * 8];
        }
#pragma unroll
        for (int ns = 0; ns < 4; ns++) {
            bf16x8 b0 = *(const bf16x8*)&lB[(wn * 64 + ns * 16 + l16) * 72 + quad * 8];
            bf16x8 b1 = *(const bf16x8*)&lB[(wn * 64 + ns * 16 + l16) * 72 + 32 + quad * 8];
#pragma unroll
            for (int ms = 0; ms < 4; ms++) {
                acc[ms][ns] = __builtin_amdgcn_mfma_f32_16x16x32_bf16(af[ms][0], b0, acc[ms][ns], 0, 0, 0);
                acc[ms][ns] = __builtin_amdgcn_mfma_f32_16x16x32_bf16(af[ms][1], b1, acc[ms][ns], 0, 0, 0);
            }
        }
    }

    if (p < 2) {
        u16* dst = p ? kb : qb;
        const float* bias = p ? bk : bq;
        const float cs = (p == 0) ? 0.18033688011112042f : 1.0f;  // log2(e)/8
        const int h = nb * 2 + wn;                // 64-col subrange = head
#pragma unroll
        for (int ns = 0; ns < 4; ns++) {
            const int ch = ns * 16 + l16;         // 0..63 within head
            const float bval = bias[h * 64 + ch];
#pragma unroll
            for (int ms = 0; ms < 4; ms++)
#pragma unroll
                for (int r = 0; r < 4; r++) {
                    const int m = mb * 128 + wq * 64 + ms * 16 + quad * 4 + r;
                    const int b = m >> 12, sq = m & (SEQ - 1);
                    dst[(((size_t)(b * NH + h) * SEQ + sq) << 6) + ch] =
                        f2bf((acc[ms][ns][r] + bval) * cs);
                }
        }
    } else {
#pragma unroll
        for (int ms = 0; ms < 4; ms++)
#pragma unroll
            for (int r = 0; r < 4; r++) {
                const int feat = mb * 128 + wq * 64 + ms * 16 + quad * 4 + r;
                const float bval = bv[feat];
                const int h = feat >> 6, hd = feat & 63;
#pragma unroll
                for (int ns = 0; ns < 4; ns++) {
                    const int n = nb * 128 + wn * 64 + ns * 16 + l16;
                    const int b = n >> 12, sq = n & (SEQ - 1);
                    // sigma: swap bits 2<->3 (PV fragment alignment, self-inverse)
                    const int sqp = (sq & ~12) | ((sq & 8) >> 1) | ((sq & 4) << 1);
                    vt[(((size_t)((b * NH + h) * HD + hd)) << 12) + sqp] =
                        f2h(acc[ms][ns][r] + bval);
                }
            }
    }
}

// --- flash attention: in-block K-split, no P exchange ------------------------
__global__ __launch_bounds__(256) void attn_kernel(
    const u16* __restrict__ qb, const u16* __restrict__ kb,
    const u16* __restrict__ vt, float* __restrict__ out)
{
    // [buf][kh][K/V][64*72] u16 = 72 KB; also aliased as fp32 combine area
    __shared__ u16 smem[2 * 2 * 2 * 64 * 72];
    float* cmb = (float*)smem;

    const int tid = threadIdx.x;
    const int wave = tid >> 6, lane = tid & 63;
    const int m31 = lane & 31, h = lane >> 5;
    const int xsw = (m31 >> 3) & 3;
    const int wq = wave >> 1, kh = wave & 1;

    // XCD swizzle: 2 bh per XCD, 32 q-blocks each
    const int blk = blockIdx.x;
    const int xcd = blk & 7, idx = blk >> 3;     // idx 0..63
    const int bh = xcd * 2 + (idx >> 5);
    const int qt = idx & 31;
    const int qbase = qt * 128 + wq * 64;

    const u16* Kb = kb + (size_t)bh * SEQ * HD;
    const u16* Vt = vt + (size_t)bh * HD * SEQ;

    bf16x8 qF[2][4];
#pragma unroll
    for (int qg = 0; qg < 2; qg++)
#pragma unroll
        for (int c = 0; c < 4; c++)
            qF[qg][c] = *(const bf16x8*)(qb + ((size_t)bh * SEQ + qbase + qg * 32 + m31) * HD
                                         + c * 16 + h * 8);

    f32x16 O[2][2];
#pragma unroll
    for (int qg = 0; qg < 2; qg++)
#pragma unroll
        for (int hg = 0; hg < 2; hg++)
#pragma unroll
            for (int j = 0; j < 16; j++) O[qg][hg][j] = 0.f;
    float l_acc[2] = {0.f, 0.f};

    u32x4 pf[8];
    // stage tile 0 into buf 0 (all 4 sub-tiles: K/V x kh0/kh1)
#pragma unroll
    for (int e = 0; e < 8; e++) {
        const int g = e * 256 + tid;
        const int tt = g >> 9, w = g & 511;
        const int kh_t = tt >> 1, kv = tt & 1;
        const int row = w >> 3, seg = w & 7, gs = seg ^ ((row >> 3) & 3);
        const int kb0 = kh_t * (SEQ / 2);
        pf[e] = kv ? *(const u32x4*)(Vt + (((size_t)row) << 12) + kb0 + gs * 8)
                   : *(const u32x4*)(Kb + (((size_t)(kb0 + row)) << 6) + gs * 8);
        *(u32x4*)&smem[(size_t)tt * (64 * 72) + row * 72 + seg * 8] = pf[e];
    }

    const int NT = (SEQ / 2) / 64;   // 32
    for (int it = 0; it < NT; it++) {
        __syncthreads();
        const int buf = it & 1;
        const u16* sK = &smem[((size_t)(buf * 2 + kh) * 2 + 0) * (64 * 72)];
        const u16* sV = &smem[((size_t)(buf * 2 + kh) * 2 + 1) * (64 * 72)];

        if (it + 1 < NT) {
#pragma unroll
            for (int e = 0; e < 8; e++) {
                const int g = e * 256 + tid;
                const int tt = g >> 9, kv = tt & 1;
                const int kh_t = tt >> 1;
                const int w = g & 511;
                const int row = w >> 3, seg = w & 7, gs = seg ^ ((row >> 3) & 3);
                const int k0 = kh_t * (SEQ / 2) + (it + 1) * 64;
                pf[e] = kv ? *(const u32x4*)(Vt + (((size_t)row) << 12) + k0 + gs * 8)
                           : *(const u32x4*)(Kb + (((size_t)(k0 + row)) << 6) + gs * 8);
            }
        }

#pragma unroll
        for (int kg = 0; kg < 2; kg++) {
            bf16x8 kA[4];
#pragma unroll
            for (int c = 0; c < 4; c++)
                kA[c] = *(const bf16x8*)&sK[(kg * 32 + m31) * 72 + (((2 * c + h) ^ xsw) << 3)];
            f16x8 vA[2][2];
#pragma unroll
            for (int hg = 0; hg < 2; hg++)
#pragma unroll
                for (int c2 = 0; c2 < 2; c2++)
                    vA[hg][c2] = *(const f16x8*)&sV[(hg * 32 + m31) * 72
                                                    + (((4 * kg + 2 * c2 + h) ^ xsw) << 3)];

#pragma unroll
            for (int qg = 0; qg < 2; qg++) {
                f32x16 St;
#pragma unroll
                for (int j = 0; j < 16; j++) St[j] = 0.f;
#pragma unroll
                for (int c = 0; c < 4; c++)
                    St = __builtin_amdgcn_mfma_f32_32x32x16_bf16(kA[c], qF[qg][c], St, 0, 0, 0);

                float ps = 0.f;
                u32 P32[8];
#pragma unroll
                for (int mm = 0; mm < 8; mm++) {
                    const float e0 = __builtin_amdgcn_exp2f(St[2 * mm]);
                    const float e1 = __builtin_amdgcn_exp2f(St[2 * mm + 1]);
                    ps += e0 + e1;
                    P32[mm] = pack_pkrtz(e0, e1);
                }
                l_acc[qg] += ps;

                u32x4 f0, f1;
                f0[0] = P32[0]; f0[1] = P32[1]; f0[2] = P32[2]; f0[3] = P32[3];
                f1[0] = P32[4]; f1[1] = P32[5]; f1[2] = P32[6]; f1[3] = P32[7];
                const f16x8 pf0 = __builtin_bit_cast(f16x8, f0);
                const f16x8 pf1 = __builtin_bit_cast(f16x8, f1);
#pragma unroll
                for (int hg = 0; hg < 2; hg++) {
                    O[qg][hg] = __builtin_amdgcn_mfma_f32_32x32x16_f16(vA[hg][0], pf0, O[qg][hg], 0, 0, 0);
                    O[qg][hg] = __builtin_amdgcn_mfma_f32_32x32x16_f16(vA[hg][1], pf1, O[qg][hg], 0, 0, 0);
                }
            }
        }

        if (it + 1 < NT) {
            u16* dstb = &smem[(size_t)((buf ^ 1) * 4) * (64 * 72)];
#pragma unroll
            for (int e = 0; e < 8; e++) {
                const int g = e * 256 + tid;
                const int tt = g >> 9, w = g & 511;
                const int row = w >> 3, seg = w & 7;
                *(u32x4*)&dstb[(size_t)tt * (64 * 72) + row * 72 + seg * 8] = pf[e];
            }
        }
    }

    // merge K-halves through LDS: kh=1 waves publish, kh=0 waves combine+store
#pragma unroll
    for (int qg = 0; qg < 2; qg++) l_acc[qg] += __shfl_xor(l_acc[qg], 32);

    __syncthreads();
    if (kh == 1) {
#pragma unroll
        for (int qg = 0; qg < 2; qg++) {
#pragma unroll
            for (int hg = 0; hg < 2; hg++)
#pragma unroll
                for (int mm = 0; mm < 4; mm++) {
                    f32x4 o;
#pragma unroll
                    for (int j = 0; j < 4; j++) o[j] = O[qg][hg][4 * mm + j];
                    *(f32x4*)&cmb[((((wq * 2 + qg) * 2 + hg) * 4 + mm) << 8) + lane * 4] = o;
                }
            cmb[32 * 256 + (wq * 2 + qg) * 64 + lane] = l_acc[qg];
        }
    }
    __syncthreads();

    if (kh == 0) {
        const int b = bh >> 3, hcol = bh & 7;
#pragma unroll
        for (int qg = 0; qg < 2; qg++) {
            const float lt = l_acc[qg] + cmb[32 * 256 + (wq * 2 + qg) * 64 + lane];
            const float inv = 1.0f / lt;
            const int sq = qbase + qg * 32 + m31;
#pragma unroll
            for (int hg = 0; hg < 2; hg++)
#pragma unroll
                for (int mm = 0; mm < 4; mm++) {
                    const f32x4 po = *(const f32x4*)&cmb[((((wq * 2 + qg) * 2 + hg) * 4 + mm) << 8) + lane * 4];
                    f32x4 o;
#pragma unroll
                    for (int j = 0; j < 4; j++) o[j] = (O[qg][hg][4 * mm + j] + po[j]) * inv;
                    *(f32x4*)&out[(((size_t)(b * SEQ + sq)) << 9) + hcol * 64
                                  + hg * 32 + 8 * mm + 4 * h] = o;
                }
        }
    }
}

// ---------------------------------------------------------------------------
extern "C" void kernel_launch(void* const* d_in, const int* in_sizes, int n_in,
                              void* d_out, int out_size, void* d_ws, size_t ws_size,
                              hipStream_t stream)
{
    const float* q  = (const float*)d_in[0];
    const float* k  = (const float*)d_in[1];
    const float* v  = (const float*)d_in[2];
    const float* Wq = (const float*)d_in[3];
    const float* bq = (const float*)d_in[4];
    const float* Wk = (const float*)d_in[5];
    const float* bk = (const float*)d_in[6];
    const float* Wv = (const float*)d_in[7];
    const float* bv = (const float*)d_in[8];
    float* out = (float*)d_out;

    // ws layout (u16): wt[3*WSZ] | qb[QSZ] | kb[QSZ] | vt[QSZ]
    u16* wt  = (u16*)d_ws;
    u16* qbp = wt  + (size_t)3 * WSZ;
    u16* kbp = qbp + (size_t)QSZ;
    u16* vtp = kbp + (size_t)QSZ;

    wt_kernel  <<<dim3(8, 8, 3), 256, 0, stream>>>(Wq, Wk, Wv, wt);
    proj_kernel<<<dim3(768),     256, 0, stream>>>(q, k, v, wt, bq, bk, bv,
                                                   qbp, kbp, vtp);
    attn_kernel<<<dim3(512),     256, 0, stream>>>(qbp, kbp, vtp, out);
}

// Round 6
// 232.527 us; speedup vs baseline: 1.0947x; 1.0947x over previous
//
#include <hip/hip_runtime.h>
#include <hip/hip_bf16.h>
#include <cstdint>

// ---------------------------------------------------------------------------
// B=2, S=4096, D=512, H=8, HD=64.
// wt: W -> W^T bf16.
// proj_qk / proj_v: 128x128-tile GEMMs, 16x16x32 bf16 MFMA, register-prefetch
//   software pipeline (load k+1 into regs during MFMA of k).
// attn: flash, S^T scheme, 32x32x16 MFMA, in-block K-split (2 wq x 2 kh),
//   K/V staged via global_load_lds DMA from global buffers stored in
//   "LDS-image" order: 8KB per 64-key tile, 16B slot = row*8 + (chunk^(row&7))
//   -> conflict-free frag reads, zero staging VALU, async double-buffer.
//   V additionally carries the sigma (swap bits 2,3) key permutation so P's
//   natural C-layout packing IS the PV B-operand fragment (no cross-lane ops).
// ---------------------------------------------------------------------------

typedef __bf16   bf16x8 __attribute__((ext_vector_type(8)));
typedef _Float16 f16x8  __attribute__((ext_vector_type(8)));
typedef float    f32x4  __attribute__((ext_vector_type(4)));
typedef float    f32x16 __attribute__((ext_vector_type(16)));
typedef unsigned int   u32;
typedef unsigned int   u32x4 __attribute__((ext_vector_type(4)));
typedef unsigned short u16;

#define NB  2
#define SEQ 4096
#define DIM 512
#define NH  8
#define HD  64
#define WSZ (DIM * DIM)
#define QSZ (NB * NH * SEQ * HD)

__device__ __forceinline__ u16 f2bf(float f) {
    __bf16 h = (__bf16)f; return __builtin_bit_cast(u16, h);
}
__device__ __forceinline__ u16 f2h(float f) {
    _Float16 h = (_Float16)f; return __builtin_bit_cast(u16, h);
}
__device__ __forceinline__ u32 pack_pkrtz(float a, float b) {
    auto pk = __builtin_amdgcn_cvt_pkrtz(a, b);
    return __builtin_bit_cast(u32, pk);
}
__device__ __forceinline__ bf16x8 cvt8p(float4 a, float4 b) {
    bf16x8 o;
    o[0]=(__bf16)a.x; o[1]=(__bf16)a.y; o[2]=(__bf16)a.z; o[3]=(__bf16)a.w;
    o[4]=(__bf16)b.x; o[5]=(__bf16)b.y; o[6]=(__bf16)b.z; o[7]=(__bf16)b.w;
    return o;
}
__device__ __forceinline__ void dma16(const u16* g, u16* l) {
    __builtin_amdgcn_global_load_lds(
        (const __attribute__((address_space(1))) u32*)g,
        (__attribute__((address_space(3))) u32*)l, 16, 0, 0);
}

// --- W transpose: WT[p][n][k] = bf16(W_p[k][n]) -----------------------------
__global__ __launch_bounds__(256) void wt_kernel(
    const float* __restrict__ Wq, const float* __restrict__ Wk,
    const float* __restrict__ Wv, u16* __restrict__ wt)
{
    __shared__ u16 lT[64 * 65];
    const int p = blockIdx.z;
    const float* W = (p == 0) ? Wq : ((p == 1) ? Wk : Wv);
    u16* dst = wt + (size_t)p * WSZ;
    const int r0 = blockIdx.x * 64, c0 = blockIdx.y * 64;
    const int t = threadIdx.x;
#pragma unroll
    for (int i = 0; i < 16; i++) {
        int idx = i * 256 + t, row = idx >> 6, col = idx & 63;
        lT[col * 65 + row] = f2bf(W[(size_t)(r0 + row) * DIM + c0 + col]);
    }
    __syncthreads();
#pragma unroll
    for (int i = 0; i < 16; i++) {
        int idx = i * 256 + t, n = idx >> 6, k = idx & 63;
        dst[(size_t)(c0 + n) * DIM + r0 + k] = lT[n * 65 + k];
    }
}

// --- proj_qk: Y = X·W for Q (p=0) and K (p=1), pipelined --------------------
__global__ __launch_bounds__(256) void proj_qk(
    const float* __restrict__ xq, const float* __restrict__ xk,
    const u16* __restrict__ wt,
    const float* __restrict__ bq, const float* __restrict__ bk,
    u16* __restrict__ qb, u16* __restrict__ kbImg)
{
    __shared__ u16 lA[128 * 72];
    __shared__ u16 lB[128 * 72];

    const int tid = threadIdx.x;
    const int wave = tid >> 6, lane = tid & 63;
    const int l16 = lane & 15, quad = lane >> 4;
    const int wq = wave >> 1, wn = wave & 1;

    const int id = blockIdx.x;
    const int p = id >> 8, r = id & 255;
    const int mb = r >> 2, nb = r & 3;
    const float* Xp = p ? xk : xq;
    const float* Af = Xp + (size_t)mb * 128 * DIM;
    const u16*   Bb = wt + (size_t)p * WSZ + (size_t)nb * 128 * DIM;

    const float* apt[4]; const u16* bpt[4]; int loff[4];
#pragma unroll
    for (int i = 0; i < 4; i++) {
        const int c = i * 256 + tid, row = c >> 3, seg = c & 7;
        apt[i] = Af + (size_t)row * DIM + seg * 8;
        bpt[i] = Bb + (size_t)row * DIM + seg * 8;
        loff[i] = row * 72 + seg * 8;
    }

    f32x4 acc[4][4];
#pragma unroll
    for (int ms = 0; ms < 4; ms++)
#pragma unroll
        for (int ns = 0; ns < 4; ns++)
#pragma unroll
            for (int j = 0; j < 4; j++) acc[ms][ns][j] = 0.f;

    float4 rA[8]; u32x4 rB[4];
#pragma unroll
    for (int i = 0; i < 4; i++) {
        rA[2*i]   = *(const float4*)(apt[i]);
        rA[2*i+1] = *(const float4*)(apt[i] + 4);
        rB[i]     = *(const u32x4*)(bpt[i]);
        apt[i] += 64; bpt[i] += 64;
    }

    for (int kt = 0; kt < 8; kt++) {
        __syncthreads();
#pragma unroll
        for (int i = 0; i < 4; i++) {
            *(bf16x8*)&lA[loff[i]] = cvt8p(rA[2*i], rA[2*i+1]);
            *(u32x4*)&lB[loff[i]]  = rB[i];
        }
        __syncthreads();
        if (kt < 7) {
#pragma unroll
            for (int i = 0; i < 4; i++) {
                rA[2*i]   = *(const float4*)(apt[i]);
                rA[2*i+1] = *(const float4*)(apt[i] + 4);
                rB[i]     = *(const u32x4*)(bpt[i]);
                apt[i] += 64; bpt[i] += 64;
            }
        }

        bf16x8 af[4][2];
#pragma unroll
        for (int ms = 0; ms < 4; ms++) {
            af[ms][0] = *(const bf16x8*)&lA[(wq * 64 + ms * 16 + l16) * 72 + quad * 8];
            af[ms][1] = *(const bf16x8*)&lA[(wq * 64 + ms * 16 + l16) * 72 + 32 + quad * 8];
        }
#pragma unroll
        for (int ns = 0; ns < 4; ns++) {
            bf16x8 b0 = *(const bf16x8*)&lB[(wn * 64 + ns * 16 + l16) * 72 + quad * 8];
            bf16x8 b1 = *(const bf16x8*)&lB[(wn * 64 + ns * 16 + l16) * 72 + 32 + quad * 8];
#pragma unroll
            for (int ms = 0; ms < 4; ms++) {
                acc[ms][ns] = __builtin_amdgcn_mfma_f32_16x16x32_bf16(af[ms][0], b0, acc[ms][ns], 0, 0, 0);
                acc[ms][ns] = __builtin_amdgcn_mfma_f32_16x16x32_bf16(af[ms][1], b1, acc[ms][ns], 0, 0, 0);
            }
        }
    }

    const float* bias = p ? bk : bq;
    const int h = nb * 2 + wn;
    if (p == 0) {
        const float cs = 0.18033688011112042f;   // log2(e)/sqrt(64)
#pragma unroll
        for (int ns = 0; ns < 4; ns++) {
            const int ch = ns * 16 + l16;
            const float bval = bias[h * 64 + ch];
#pragma unroll
            for (int ms = 0; ms < 4; ms++)
#pragma unroll
                for (int rr = 0; rr < 4; rr++) {
                    const int m = mb * 128 + wq * 64 + ms * 16 + quad * 4 + rr;
                    const int b = m >> 12, sq = m & (SEQ - 1);
                    qb[(((size_t)(b * NH + h) * SEQ + sq) << 6) + ch] =
                        f2bf((acc[ms][ns][rr] + bval) * cs);
                }
        }
    } else {
#pragma unroll
        for (int ns = 0; ns < 4; ns++) {
            const int ch = ns * 16 + l16;
            const float bval = bias[h * 64 + ch];
#pragma unroll
            for (int ms = 0; ms < 4; ms++)
#pragma unroll
                for (int rr = 0; rr < 4; rr++) {
                    const int m = mb * 128 + wq * 64 + ms * 16 + quad * 4 + rr;
                    const int b = m >> 12, sq = m & (SEQ - 1);
                    const int bh = b * NH + h;
                    const size_t idx = ((size_t)(bh * 64 + (sq >> 6))) * 4096
                                     + (sq & 63) * 64
                                     + (((ch >> 3) ^ (sq & 7)) << 3) + (ch & 7);
                    kbImg[idx] = f2bf(acc[ms][ns][rr] + bval);
                }
        }
    }
}

// --- proj_v: V^T image, pipelined ------------------------------------------
__global__ __launch_bounds__(256) void proj_v(
    const float* __restrict__ xv, const u16* __restrict__ wt,
    const float* __restrict__ bv, u16* __restrict__ vtImg)
{
    __shared__ u16 lA[128 * 72];
    __shared__ u16 lB[128 * 72];

    const int tid = threadIdx.x;
    const int wave = tid >> 6, lane = tid & 63;
    const int l16 = lane & 15, quad = lane >> 4;
    const int wq = wave >> 1, wn = wave & 1;

    const int mb = blockIdx.x >> 6, nb = blockIdx.x & 63;   // 4 x 64
    const u16*   Ab = wt + (size_t)2 * WSZ + (size_t)mb * 128 * DIM;
    const float* Bf = xv + (size_t)nb * 128 * DIM;

    const u16* apt[4]; const float* bpt[4]; int loff[4];
#pragma unroll
    for (int i = 0; i < 4; i++) {
        const int c = i * 256 + tid, row = c >> 3, seg = c & 7;
        apt[i] = Ab + (size_t)row * DIM + seg * 8;
        bpt[i] = Bf + (size_t)row * DIM + seg * 8;
        loff[i] = row * 72 + seg * 8;
    }

    f32x4 acc[4][4];
#pragma unroll
    for (int ms = 0; ms < 4; ms++)
#pragma unroll
        for (int ns = 0; ns < 4; ns++)
#pragma unroll
            for (int j = 0; j < 4; j++) acc[ms][ns][j] = 0.f;

    u32x4 rA[4]; float4 rB[8];
#pragma unroll
    for (int i = 0; i < 4; i++) {
        rA[i]     = *(const u32x4*)(apt[i]);
        rB[2*i]   = *(const float4*)(bpt[i]);
        rB[2*i+1] = *(const float4*)(bpt[i] + 4);
        apt[i] += 64; bpt[i] += 64;
    }

    for (int kt = 0; kt < 8; kt++) {
        __syncthreads();
#pragma unroll
        for (int i = 0; i < 4; i++) {
            *(u32x4*)&lA[loff[i]]  = rA[i];
            *(bf16x8*)&lB[loff[i]] = cvt8p(rB[2*i], rB[2*i+1]);
        }
        __syncthreads();
        if (kt < 7) {
#pragma unroll
            for (int i = 0; i < 4; i++) {
                rA[i]     = *(const u32x4*)(apt[i]);
                rB[2*i]   = *(const float4*)(bpt[i]);
                rB[2*i+1] = *(const float4*)(bpt[i] + 4);
                apt[i] += 64; bpt[i] += 64;
            }
        }

        bf16x8 af[4][2];
#pragma unroll
        for (int ms = 0; ms < 4; ms++) {
            af[ms][0] = *(const bf16x8*)&lA[(wq * 64 + ms * 16 + l16) * 72 + quad * 8];
            af[ms][1] = *(const bf16x8*)&lA[(wq * 64 + ms * 16 + l16) * 72 + 32 + quad * 8];
        }
#pragma unroll
        for (int ns = 0; ns < 4; ns++) {
            bf16x8 b0 = *(const bf16x8*)&lB[(wn * 64 + ns * 16 + l16) * 72 + quad * 8];
            bf16x8 b1 = *(const bf16x8*)&lB[(wn * 64 + ns * 16 + l16) * 72 + 32 + quad * 8];
#pragma unroll
            for (int ms = 0; ms < 4; ms++) {
                acc[ms][ns] = __builtin_amdgcn_mfma_f32_16x16x32_bf16(af[ms][0], b0, acc[ms][ns], 0, 0, 0);
                acc[ms][ns] = __builtin_amdgcn_mfma_f32_16x16x32_bf16(af[ms][1], b1, acc[ms][ns], 0, 0, 0);
            }
        }
    }

#pragma unroll
    for (int ms = 0; ms < 4; ms++)
#pragma unroll
        for (int rr = 0; rr < 4; rr++) {
            const int feat = mb * 128 + wq * 64 + ms * 16 + quad * 4 + rr;
            const float bval = bv[feat];
            const int h = feat >> 6, hd = feat & 63;
#pragma unroll
            for (int ns = 0; ns < 4; ns++) {
                const int n = nb * 128 + wn * 64 + ns * 16 + l16;
                const int b = n >> 12, sq = n & (SEQ - 1);
                const int sqp = (sq & ~12) | ((sq & 8) >> 1) | ((sq & 4) << 1);
                const int bh = b * NH + h;
                const size_t idx = ((size_t)(bh * 64 + (sq >> 6))) * 4096
                                 + (size_t)hd * 64
                                 + ((((sqp >> 3) & 7) ^ (hd & 7)) << 3) + (sqp & 7);
                vtImg[idx] = f2h(acc[ms][ns][rr] + bval);
            }
        }
}

// --- flash attention: DMA-staged, in-block K-split, no P exchange ------------
__global__ __launch_bounds__(256) void attn_kernel(
    const u16* __restrict__ qb, const u16* __restrict__ kbImg,
    const u16* __restrict__ vtImg, float* __restrict__ out)
{
    __shared__ u16 smem[2 * 4 * 4096];   // [buf][subtile: kh*2+kv][8KB] = 64KB
    float* cmb = (float*)smem;

    const int tid = threadIdx.x;
    const int wave = tid >> 6, lane = tid & 63;
    const int m31 = lane & 31, h = lane >> 5;
    const int x7 = m31 & 7;
    const int wq = wave >> 1, kh = wave & 1;

    const int blk = blockIdx.x;
    const int xcd = blk & 7, idx = blk >> 3;
    const int bh = xcd * 2 + (idx >> 5);
    const int qt = idx & 31;
    const int qbase = qt * 128 + wq * 64;

    // Q B-frags from linear qb
    bf16x8 qF[2][4];
#pragma unroll
    for (int qg = 0; qg < 2; qg++)
#pragma unroll
        for (int c = 0; c < 4; c++)
            qF[qg][c] = *(const bf16x8*)(qb + ((size_t)bh * SEQ + qbase + qg * 32 + m31) * HD
                                         + c * 16 + h * 8);

    f32x16 O[2][2];
#pragma unroll
    for (int qg = 0; qg < 2; qg++)
#pragma unroll
        for (int hg = 0; hg < 2; hg++)
#pragma unroll
            for (int j = 0; j < 16; j++) O[qg][hg][j] = 0.f;
    float l_acc[2] = {0.f, 0.f};

    // DMA: wave w stages subtile w (kh_t = w>>1, kv = w&1), 8 x 1KB segs
    const u16* img = (wave & 1) ? vtImg : kbImg;
    const u16* gp = img + ((size_t)(bh * 64 + (wave >> 1) * 32)) * 4096 + lane * 8;
    {
        u16* lb = smem + wave * 4096;
#pragma unroll
        for (int e = 0; e < 8; e++) dma16(gp + e * 512, lb + e * 512);
        gp += 4096;
    }

    const int NT = 32;
    for (int it = 0; it < NT; it++) {
        __syncthreads();                       // drains this tile's DMA
        if (it + 1 < NT) {
            u16* lb = smem + (((it + 1) & 1) * 4 + wave) * 4096;
#pragma unroll
            for (int e = 0; e < 8; e++) dma16(gp + e * 512, lb + e * 512);
            gp += 4096;
        }
        const int buf = it & 1;
        const u16* sK = smem + (size_t)(buf * 4 + kh * 2) * 4096;
        const u16* sV = sK + 4096;

#pragma unroll
        for (int kg = 0; kg < 2; kg++) {
            bf16x8 kA[4];
#pragma unroll
            for (int c = 0; c < 4; c++)
                kA[c] = *(const bf16x8*)&sK[((kg * 32 + m31) << 6) + (((2 * c + h) ^ x7) << 3)];
            f16x8 vA[2][2];
#pragma unroll
            for (int hg = 0; hg < 2; hg++)
#pragma unroll
                for (int c2 = 0; c2 < 2; c2++)
                    vA[hg][c2] = *(const f16x8*)&sV[((hg * 32 + m31) << 6)
                                                    + (((4 * kg + 2 * c2 + h) ^ x7) << 3)];

#pragma unroll
            for (int qg = 0; qg < 2; qg++) {
                f32x16 St;
#pragma unroll
                for (int j = 0; j < 16; j++) St[j] = 0.f;
#pragma unroll
                for (int c = 0; c < 4; c++)
                    St = __builtin_amdgcn_mfma_f32_32x32x16_bf16(kA[c], qF[qg][c], St, 0, 0, 0);

                float ps = 0.f;
                u32 P32[8];
#pragma unroll
                for (int mm = 0; mm < 8; mm++) {
                    const float e0 = __builtin_amdgcn_exp2f(St[2 * mm]);
                    const float e1 = __builtin_amdgcn_exp2f(St[2 * mm + 1]);
                    ps += e0 + e1;
                    P32[mm] = pack_pkrtz(e0, e1);
                }
                l_acc[qg] += ps;

                u32x4 f0, f1;
                f0[0] = P32[0]; f0[1] = P32[1]; f0[2] = P32[2]; f0[3] = P32[3];
                f1[0] = P32[4]; f1[1] = P32[5]; f1[2] = P32[6]; f1[3] = P32[7];
                const f16x8 pf0 = __builtin_bit_cast(f16x8, f0);
                const f16x8 pf1 = __builtin_bit_cast(f16x8, f1);
#pragma unroll
                for (int hg = 0; hg < 2; hg++) {
                    O[qg][hg] = __builtin_amdgcn_mfma_f32_32x32x16_f16(vA[hg][0], pf0, O[qg][hg], 0, 0, 0);
                    O[qg][hg] = __builtin_amdgcn_mfma_f32_32x32x16_f16(vA[hg][1], pf1, O[qg][hg], 0, 0, 0);
                }
            }
        }
    }

    // merge K-halves through LDS: kh=1 publishes, kh=0 combines + stores
#pragma unroll
    for (int qg = 0; qg < 2; qg++) l_acc[qg] += __shfl_xor(l_acc[qg], 32);

    __syncthreads();
    if (kh == 1) {
#pragma unroll
        for (int qg = 0; qg < 2; qg++) {
#pragma unroll
            for (int hg = 0; hg < 2; hg++)
#pragma unroll
                for (int mm = 0; mm < 4; mm++) {
                    f32x4 o;
#pragma unroll
                    for (int j = 0; j < 4; j++) o[j] = O[qg][hg][4 * mm + j];
                    *(f32x4*)&cmb[((((wq * 2 + qg) * 2 + hg) * 4 + mm) << 8) + lane * 4] = o;
                }
            cmb[32 * 256 + (wq * 2 + qg) * 64 + lane] = l_acc[qg];
        }
    }
    __syncthreads();

    if (kh == 0) {
        const int b = bh >> 3, hcol = bh & 7;
#pragma unroll
        for (int qg = 0; qg < 2; qg++) {
            const float lt = l_acc[qg] + cmb[32 * 256 + (wq * 2 + qg) * 64 + lane];
            const float inv = 1.0f / lt;
            const int sq = qbase + qg * 32 + m31;
#pragma unroll
            for (int hg = 0; hg < 2; hg++)
#pragma unroll
                for (int mm = 0; mm < 4; mm++) {
                    const f32x4 po = *(const f32x4*)&cmb[((((wq * 2 + qg) * 2 + hg) * 4 + mm) << 8) + lane * 4];
                    f32x4 o;
#pragma unroll
                    for (int j = 0; j < 4; j++) o[j] = (O[qg][hg][4 * mm + j] + po[j]) * inv;
                    *(f32x4*)&out[(((size_t)(b * SEQ + sq)) << 9) + hcol * 64
                                  + hg * 32 + 8 * mm + 4 * h] = o;
                }
        }
    }
}

// ---------------------------------------------------------------------------
extern "C" void kernel_launch(void* const* d_in, const int* in_sizes, int n_in,
                              void* d_out, int out_size, void* d_ws, size_t ws_size,
                              hipStream_t stream)
{
    const float* q  = (const float*)d_in[0];
    const float* k  = (const float*)d_in[1];
    const float* v  = (const float*)d_in[2];
    const float* Wq = (const float*)d_in[3];
    const float* bq = (const float*)d_in[4];
    const float* Wk = (const float*)d_in[5];
    const float* bk = (const float*)d_in[6];
    const float* Wv = (const float*)d_in[7];
    const float* bv = (const float*)d_in[8];
    float* out = (float*)d_out;

    // ws layout (u16): wt[3*WSZ] | qb[QSZ] | kbImg[QSZ] | vtImg[QSZ]
    u16* wt  = (u16*)d_ws;
    u16* qbp = wt  + (size_t)3 * WSZ;
    u16* kbp = qbp + (size_t)QSZ;
    u16* vtp = kbp + (size_t)QSZ;

    wt_kernel<<<dim3(8, 8, 3), 256, 0, stream>>>(Wq, Wk, Wv, wt);
    proj_qk  <<<dim3(512),     256, 0, stream>>>(q, k, wt, bq, bk, qbp, kbp);
    proj_v   <<<dim3(256),     256, 0, stream>>>(v, wt, bv, vtp);
    attn_kernel<<<dim3(512),   256, 0, stream>>>(qbp, kbp, vtp, out);
}

// Round 7
// 219.232 us; speedup vs baseline: 1.1611x; 1.0606x over previous
//
#include <hip/hip_runtime.h>
#include <hip/hip_bf16.h>
#include <cstdint>

// ---------------------------------------------------------------------------
// B=2, S=4096, D=512, H=8, HD=64.
// wt: W -> W^T bf16.
// proj (fused QKV, 768 blocks): 128x128 tiles, 16x16x32 bf16 MFMA, register
//   software pipeline; epilogue stages the output tile in LDS in the exact
//   global image order, then dumps linear b128 stores (no scattered stores).
// attn: flash, S^T scheme, 32x32x16 MFMA. 512-thread blocks: 8 waves =
//   4 q-waves (32 q each) x 2 K-halves sharing 64KB double-buffered LDS
//   -> 2 blocks/CU, 4 waves/SIMD. K/V staged with global_load_lds from
//   "LDS-image" buffers; image swizzle chunk ^ ((row^(row>>3))&7) makes all
//   frag reads bank-conflict-free. V carries the sigma(swap bits 2,3) key
//   permutation so P's C-layout packing IS the PV B-fragment (no cross-lane).
// ---------------------------------------------------------------------------

typedef __bf16   bf16x8 __attribute__((ext_vector_type(8)));
typedef _Float16 f16x8  __attribute__((ext_vector_type(8)));
typedef float    f32x4  __attribute__((ext_vector_type(4)));
typedef float    f32x16 __attribute__((ext_vector_type(16)));
typedef unsigned int   u32;
typedef unsigned int   u32x4 __attribute__((ext_vector_type(4)));
typedef unsigned short u16;

#define NB  2
#define SEQ 4096
#define DIM 512
#define NH  8
#define HD  64
#define WSZ (DIM * DIM)
#define QSZ (NB * NH * SEQ * HD)

__device__ __forceinline__ u16 f2bf(float f) {
    __bf16 h = (__bf16)f; return __builtin_bit_cast(u16, h);
}
__device__ __forceinline__ u16 f2h(float f) {
    _Float16 h = (_Float16)f; return __builtin_bit_cast(u16, h);
}
__device__ __forceinline__ u32 pack_pkrtz(float a, float b) {
    auto pk = __builtin_amdgcn_cvt_pkrtz(a, b);
    return __builtin_bit_cast(u32, pk);
}
__device__ __forceinline__ bf16x8 cvt8p(float4 a, float4 b) {
    bf16x8 o;
    o[0]=(__bf16)a.x; o[1]=(__bf16)a.y; o[2]=(__bf16)a.z; o[3]=(__bf16)a.w;
    o[4]=(__bf16)b.x; o[5]=(__bf16)b.y; o[6]=(__bf16)b.z; o[7]=(__bf16)b.w;
    return o;
}
__device__ __forceinline__ void dma16(const u16* g, u16* l) {
    __builtin_amdgcn_global_load_lds(
        (const __attribute__((address_space(1))) u32*)g,
        (__attribute__((address_space(3))) u32*)l, 16, 0, 0);
}

// --- W transpose: WT[p][n][k] = bf16(W_p[k][n]) -----------------------------
__global__ __launch_bounds__(256) void wt_kernel(
    const float* __restrict__ Wq, const float* __restrict__ Wk,
    const float* __restrict__ Wv, u16* __restrict__ wt)
{
    __shared__ u16 lT[64 * 65];
    const int p = blockIdx.z;
    const float* W = (p == 0) ? Wq : ((p == 1) ? Wk : Wv);
    u16* dst = wt + (size_t)p * WSZ;
    const int r0 = blockIdx.x * 64, c0 = blockIdx.y * 64;
    const int t = threadIdx.x;
#pragma unroll
    for (int i = 0; i < 16; i++) {
        int idx = i * 256 + t, row = idx >> 6, col = idx & 63;
        lT[col * 65 + row] = f2bf(W[(size_t)(r0 + row) * DIM + c0 + col]);
    }
    __syncthreads();
#pragma unroll
    for (int i = 0; i < 16; i++) {
        int idx = i * 256 + t, n = idx >> 6, k = idx & 63;
        dst[(size_t)(c0 + n) * DIM + r0 + k] = lT[n * 65 + k];
    }
}

// --- fused projection GEMM: 128x128 tiles, LDS-staged coalesced epilogue ----
__global__ __launch_bounds__(256) void proj_kernel(
    const float* __restrict__ xq, const float* __restrict__ xk,
    const float* __restrict__ xv, const u16* __restrict__ wt,
    const float* __restrict__ bq, const float* __restrict__ bk,
    const float* __restrict__ bv,
    u16* __restrict__ qb, u16* __restrict__ kbImg, u16* __restrict__ vtImg)
{
    __shared__ u16 smem[2 * 128 * 72];           // lA | lB ; epilogue: 32KB tile
    u16* lA = smem;
    u16* lB = smem + 128 * 72;

    const int tid = threadIdx.x;
    const int wave = tid >> 6, lane = tid & 63;
    const int l16 = lane & 15, quad = lane >> 4;
    const int wq = wave >> 1, wn = wave & 1;

    int p, mb, nb;
    {
        const int id = blockIdx.x;
        if (id < 512) { p = id >> 8; const int r = id & 255; mb = r >> 2; nb = r & 3; }
        else          { p = 2; const int r = id - 512; mb = r >> 6; nb = r & 63; }
    }
    const float* Xp = (p == 0) ? xq : ((p == 1) ? xk : xv);
    const u16*   Wp = wt + (size_t)p * WSZ;
    const bool cvtA = (p < 2);
    // rf = fp32 source rows, rb = bf16 source rows
    const float* Ff = cvtA ? (Xp + (size_t)mb * 128 * DIM) : (Xp + (size_t)nb * 128 * DIM);
    const u16*   Fb = cvtA ? (Wp + (size_t)nb * 128 * DIM) : (Wp + (size_t)mb * 128 * DIM);

    const float* pf[4]; const u16* pb[4]; int loff[4];
#pragma unroll
    for (int i = 0; i < 4; i++) {
        const int c = i * 256 + tid, row = c >> 3, seg = c & 7;
        pf[i] = Ff + (size_t)row * DIM + seg * 8;
        pb[i] = Fb + (size_t)row * DIM + seg * 8;
        loff[i] = row * 72 + seg * 8;
    }

    f32x4 acc[4][4];
#pragma unroll
    for (int ms = 0; ms < 4; ms++)
#pragma unroll
        for (int ns = 0; ns < 4; ns++)
#pragma unroll
            for (int j = 0; j < 4; j++) acc[ms][ns][j] = 0.f;

    float4 rf[8]; u32x4 rb[4];
#pragma unroll
    for (int i = 0; i < 4; i++) {
        rf[2*i]   = *(const float4*)(pf[i]);
        rf[2*i+1] = *(const float4*)(pf[i] + 4);
        rb[i]     = *(const u32x4*)(pb[i]);
        pf[i] += 64; pb[i] += 64;
    }

    for (int kt = 0; kt < 8; kt++) {
        __syncthreads();
#pragma unroll
        for (int i = 0; i < 4; i++) {
            if (cvtA) {
                *(bf16x8*)&lA[loff[i]] = cvt8p(rf[2*i], rf[2*i+1]);
                *(u32x4*)&lB[loff[i]]  = rb[i];
            } else {
                *(u32x4*)&lA[loff[i]]  = rb[i];
                *(bf16x8*)&lB[loff[i]] = cvt8p(rf[2*i], rf[2*i+1]);
            }
        }
        __syncthreads();
        if (kt < 7) {
#pragma unroll
            for (int i = 0; i < 4; i++) {
                rf[2*i]   = *(const float4*)(pf[i]);
                rf[2*i+1] = *(const float4*)(pf[i] + 4);
                rb[i]     = *(const u32x4*)(pb[i]);
                pf[i] += 64; pb[i] += 64;
            }
        }

        bf16x8 af[4][2];
#pragma unroll
        for (int ms = 0; ms < 4; ms++) {
            af[ms][0] = *(const bf16x8*)&lA[(wq * 64 + ms * 16 + l16) * 72 + quad * 8];
            af[ms][1] = *(const bf16x8*)&lA[(wq * 64 + ms * 16 + l16) * 72 + 32 + quad * 8];
        }
#pragma unroll
        for (int ns = 0; ns < 4; ns++) {
            bf16x8 b0 = *(const bf16x8*)&lB[(wn * 64 + ns * 16 + l16) * 72 + quad * 8];
            bf16x8 b1 = *(const bf16x8*)&lB[(wn * 64 + ns * 16 + l16) * 72 + 32 + quad * 8];
#pragma unroll
            for (int ms = 0; ms < 4; ms++) {
                acc[ms][ns] = __builtin_amdgcn_mfma_f32_16x16x32_bf16(af[ms][0], b0, acc[ms][ns], 0, 0, 0);
                acc[ms][ns] = __builtin_amdgcn_mfma_f32_16x16x32_bf16(af[ms][1], b1, acc[ms][ns], 0, 0, 0);
            }
        }
    }

    // ---- epilogue: stage tile in LDS in output-image order, dump linearly ---
    __syncthreads();
    if (p < 2) {
        const float* bias = p ? bk : bq;
        const float cs = (p == 0) ? 0.18033688011112042f : 1.0f;   // log2e/8
        const int stl = wn * 2 + wq;
        const int hh = nb * 2 + wn;
#pragma unroll
        for (int ns = 0; ns < 4; ns++) {
            const int ch = ns * 16 + l16;
            const float bval = bias[hh * 64 + ch];
#pragma unroll
            for (int ms = 0; ms < 4; ms++)
#pragma unroll
                for (int rr = 0; rr < 4; rr++) {
                    const int sqL = ms * 16 + quad * 4 + rr;
                    const float v = (acc[ms][ns][rr] + bval) * cs;
                    int off;
                    if (p == 0) off = sqL * 64 + ch;
                    else        off = sqL * 64 +
                                      (((ch >> 3) ^ ((sqL ^ (sqL >> 3)) & 7)) << 3) + (ch & 7);
                    smem[stl * 4096 + off] = f2bf(v);
                }
        }
    } else {
        const int stl = wq * 2 + wn;
#pragma unroll
        for (int ms = 0; ms < 4; ms++)
#pragma unroll
            for (int rr = 0; rr < 4; rr++) {
                const int hd = ms * 16 + quad * 4 + rr;
                const float bval = bv[mb * 128 + wq * 64 + hd];
                const int swh = (hd ^ (hd >> 3)) & 7;
#pragma unroll
                for (int ns = 0; ns < 4; ns++) {
                    const int nl = ns * 16 + l16;
                    const int sqpL = (nl & ~12) | ((nl & 8) >> 1) | ((nl & 4) << 1);
                    smem[stl * 4096 + hd * 64 +
                         (((sqpL >> 3) ^ swh) << 3) + (sqpL & 7)] =
                        f2h(acc[ms][ns][rr] + bval);
                }
            }
    }
    __syncthreads();

    {
        u16* dstp; size_t gbase;
        if (p < 2) {
            const int hh = nb * 2 + (wave >> 1);
            const int b2 = mb >> 5;
            const int row0 = (mb * 128 + (wave & 1) * 64) & 4095;
            if (p == 0) { dstp = qb;    gbase = ((size_t)(b2 * NH + hh) * 4096 + row0) * 64; }
            else        { dstp = kbImg; gbase = ((size_t)((b2 * NH + hh) * 64 + (row0 >> 6))) * 4096; }
        } else {
            const int hh = mb * 2 + (wave >> 1);
            const int b2 = nb >> 5;
            const int nblk = (nb & 31) * 2 + (wave & 1);
            dstp = vtImg; gbase = ((size_t)((b2 * NH + hh) * 64 + nblk)) * 4096;
        }
#pragma unroll
        for (int e = 0; e < 8; e++) {
            const u32x4 vv = *(const u32x4*)&smem[wave * 4096 + e * 512 + lane * 8];
            *(u32x4*)(dstp + gbase + e * 512 + lane * 8) = vv;
        }
    }
}

// --- flash attention: 512 threads, 4 wq x 2 kh, DMA double-buffer ------------
__global__ __launch_bounds__(512, 4) void attn_kernel(
    const u16* __restrict__ qb, const u16* __restrict__ kbImg,
    const u16* __restrict__ vtImg, float* __restrict__ out)
{
    __shared__ u16 smem[2 * 4 * 4096];   // [buf][kh*2+kv][8KB] = 64KB
    float* cmb = (float*)smem;

    const int tid = threadIdx.x;
    const int wave = tid >> 6, lane = tid & 63;
    const int m31 = lane & 31, h = lane >> 5;
    const int wq = wave >> 1, kh = wave & 1;

    const int blk = blockIdx.x;
    const int xcd = blk & 7, idx = blk >> 3;
    const int bh = xcd * 2 + (idx >> 5);
    const int qt = idx & 31;
    const int qbase = qt * 128 + wq * 32;

    bf16x8 qF[4];
#pragma unroll
    for (int c = 0; c < 4; c++)
        qF[c] = *(const bf16x8*)(qb + ((size_t)bh * SEQ + qbase + m31) * HD + c * 16 + h * 8);

    f32x16 O0, O1;
#pragma unroll
    for (int j = 0; j < 16; j++) { O0[j] = 0.f; O1[j] = 0.f; }
    float l_acc = 0.f;

    // DMA: wave pair stages one subtile; st = wave>>1 (khT = st>>1, kv = st&1)
    const int st  = wave >> 1;
    const int hw  = wave & 1;
    const u16* img = (st & 1) ? vtImg : kbImg;
    const u16* gp = img + ((size_t)(bh * 64 + (st >> 1) * 32)) * 4096 + hw * 2048 + lane * 8;
    {
        u16* lb = smem + st * 4096 + hw * 2048 + lane * 8;
#pragma unroll
        for (int e = 0; e < 4; e++) dma16(gp + e * 512, lb + e * 512);
        gp += 4096;
    }

    const int NT = 32;
    for (int it = 0; it < NT; it++) {
        __syncthreads();
        if (it + 1 < NT) {
            u16* lb = smem + ((((it + 1) & 1) * 4 + st)) * 4096 + hw * 2048 + lane * 8;
#pragma unroll
            for (int e = 0; e < 4; e++) dma16(gp + e * 512, lb + e * 512);
            gp += 4096;
        }
        const u16* sK = smem + (size_t)(((it & 1) * 4) + kh * 2) * 4096;
        const u16* sV = sK + 4096;

#pragma unroll
        for (int kg = 0; kg < 2; kg++) {
            const int rK = kg * 32 + m31;
            const int swK = (rK ^ (rK >> 3)) & 7;
            bf16x8 kA[4];
#pragma unroll
            for (int c = 0; c < 4; c++)
                kA[c] = *(const bf16x8*)&sK[(rK << 6) + (((2 * c + h) ^ swK) << 3)];

            const int swV0 = (m31 ^ (m31 >> 3)) & 7;
            const int rV1 = 32 + m31;
            const int swV1 = (rV1 ^ (rV1 >> 3)) & 7;
            f16x8 vA0[2], vA1[2];
#pragma unroll
            for (int c2 = 0; c2 < 2; c2++) {
                vA0[c2] = *(const f16x8*)&sV[(m31 << 6) + (((4 * kg + 2 * c2 + h) ^ swV0) << 3)];
                vA1[c2] = *(const f16x8*)&sV[(rV1 << 6) + (((4 * kg + 2 * c2 + h) ^ swV1) << 3)];
            }

            f32x16 Sv;
#pragma unroll
            for (int j = 0; j < 16; j++) Sv[j] = 0.f;
#pragma unroll
            for (int c = 0; c < 4; c++)
                Sv = __builtin_amdgcn_mfma_f32_32x32x16_bf16(kA[c], qF[c], Sv, 0, 0, 0);

            float ps = 0.f;
            u32 P32[8];
#pragma unroll
            for (int mm = 0; mm < 8; mm++) {
                const float e0 = __builtin_amdgcn_exp2f(Sv[2 * mm]);
                const float e1 = __builtin_amdgcn_exp2f(Sv[2 * mm + 1]);
                ps += e0 + e1;
                P32[mm] = pack_pkrtz(e0, e1);
            }
            l_acc += ps;

            u32x4 f0, f1;
            f0[0] = P32[0]; f0[1] = P32[1]; f0[2] = P32[2]; f0[3] = P32[3];
            f1[0] = P32[4]; f1[1] = P32[5]; f1[2] = P32[6]; f1[3] = P32[7];
            const f16x8 pf0 = __builtin_bit_cast(f16x8, f0);
            const f16x8 pf1 = __builtin_bit_cast(f16x8, f1);
            O0 = __builtin_amdgcn_mfma_f32_32x32x16_f16(vA0[0], pf0, O0, 0, 0, 0);
            O0 = __builtin_amdgcn_mfma_f32_32x32x16_f16(vA0[1], pf1, O0, 0, 0, 0);
            O1 = __builtin_amdgcn_mfma_f32_32x32x16_f16(vA1[0], pf0, O1, 0, 0, 0);
            O1 = __builtin_amdgcn_mfma_f32_32x32x16_f16(vA1[1], pf1, O1, 0, 0, 0);
        }
    }

    // merge the two K-halves through LDS
    l_acc += __shfl_xor(l_acc, 32);
    __syncthreads();
    if (kh == 1) {
#pragma unroll
        for (int hg = 0; hg < 2; hg++)
#pragma unroll
            for (int mm = 0; mm < 4; mm++) {
                f32x4 o;
#pragma unroll
                for (int j = 0; j < 4; j++) o[j] = (hg ? O1 : O0)[4 * mm + j];
                *(f32x4*)&cmb[(((wq * 2 + hg) * 4 + mm) << 8) + lane * 4] = o;
            }
        cmb[8192 + wq * 64 + lane] = l_acc;
    }
    __syncthreads();

    if (kh == 0) {
        const int b = bh >> 3, hcol = bh & 7;
        const float lt = l_acc + cmb[8192 + wq * 64 + lane];
        const float inv = 1.0f / lt;
        const int sq = qbase + m31;
#pragma unroll
        for (int hg = 0; hg < 2; hg++)
#pragma unroll
            for (int mm = 0; mm < 4; mm++) {
                const f32x4 po = *(const f32x4*)&cmb[(((wq * 2 + hg) * 4 + mm) << 8) + lane * 4];
                f32x4 o;
#pragma unroll
                for (int j = 0; j < 4; j++)
                    o[j] = ((hg ? O1 : O0)[4 * mm + j] + po[j]) * inv;
                *(f32x4*)&out[(((size_t)(b * SEQ + sq)) << 9) + hcol * 64
                              + hg * 32 + 8 * mm + 4 * h] = o;
            }
    }
}

// ---------------------------------------------------------------------------
extern "C" void kernel_launch(void* const* d_in, const int* in_sizes, int n_in,
                              void* d_out, int out_size, void* d_ws, size_t ws_size,
                              hipStream_t stream)
{
    const float* q  = (const float*)d_in[0];
    const float* k  = (const float*)d_in[1];
    const float* v  = (const float*)d_in[2];
    const float* Wq = (const float*)d_in[3];
    const float* bq = (const float*)d_in[4];
    const float* Wk = (const float*)d_in[5];
    const float* bk = (const float*)d_in[6];
    const float* Wv = (const float*)d_in[7];
    const float* bv = (const float*)d_in[8];
    float* out = (float*)d_out;

    // ws layout (u16): wt[3*WSZ] | qb[QSZ] | kbImg[QSZ] | vtImg[QSZ]
    u16* wt  = (u16*)d_ws;
    u16* qbp = wt  + (size_t)3 * WSZ;
    u16* kbp = qbp + (size_t)QSZ;
    u16* vtp = kbp + (size_t)QSZ;

    wt_kernel  <<<dim3(8, 8, 3), 256, 0, stream>>>(Wq, Wk, Wv, wt);
    proj_kernel<<<dim3(768),     256, 0, stream>>>(q, k, v, wt, bq, bk, bv,
                                                   qbp, kbp, vtp);
    attn_kernel<<<dim3(512),     512, 0, stream>>>(qbp, kbp, vtp, out);
}

// Round 8
// 216.404 us; speedup vs baseline: 1.1763x; 1.0131x over previous
//
#include <hip/hip_runtime.h>
#include <hip/hip_bf16.h>
#include <cstdint>

// ---------------------------------------------------------------------------
// B=2, S=4096, D=512, H=8, HD=64.
// xcvt: X fp32 -> bf16 "proj image": per (mtile,kslab) a 128x32 slab, in-slab
//       offset = row*32 + ((chunk ^ ((row^(row>>2))&3))<<3) + (k&7).
// wt:   W -> W^T bf16 in the same image format.
// proj: all-bf16 128x128-tile GEMM, both operands DMA-staged (global_load_lds)
//       from images, 2x16KB double buffer, 16 K-iters, XCD-pinned tile groups
//       (4 nb-tiles sharing an X-tile on one XCD -> L2 reuse). Epilogue stages
//       output tile in LDS in global image order, dumps linear b128 stores.
// attn: unchanged from round 7 (S^T scheme, 32x32x16, 512 thr, 4wq x 2kh,
//       DMA double-buffer, V sigma-permuted so P feeds PV directly).
// ---------------------------------------------------------------------------

typedef __bf16   bf16x8 __attribute__((ext_vector_type(8)));
typedef _Float16 f16x8  __attribute__((ext_vector_type(8)));
typedef float    f32x4  __attribute__((ext_vector_type(4)));
typedef float    f32x16 __attribute__((ext_vector_type(16)));
typedef unsigned int   u32;
typedef unsigned int   u32x4 __attribute__((ext_vector_type(4)));
typedef unsigned short u16;

#define NB  2
#define SEQ 4096
#define DIM 512
#define NH  8
#define HD  64
#define WSZ (DIM * DIM)
#define XSZ (NB * SEQ * DIM)
#define QSZ (NB * NH * SEQ * HD)

__device__ __forceinline__ u16 f2bf(float f) {
    __bf16 h = (__bf16)f; return __builtin_bit_cast(u16, h);
}
__device__ __forceinline__ u16 f2h(float f) {
    _Float16 h = (_Float16)f; return __builtin_bit_cast(u16, h);
}
__device__ __forceinline__ u32 pack_pkrtz(float a, float b) {
    auto pk = __builtin_amdgcn_cvt_pkrtz(a, b);
    return __builtin_bit_cast(u32, pk);
}
__device__ __forceinline__ bf16x8 cvt8p(float4 a, float4 b) {
    bf16x8 o;
    o[0]=(__bf16)a.x; o[1]=(__bf16)a.y; o[2]=(__bf16)a.z; o[3]=(__bf16)a.w;
    o[4]=(__bf16)b.x; o[5]=(__bf16)b.y; o[6]=(__bf16)b.z; o[7]=(__bf16)b.w;
    return o;
}
__device__ __forceinline__ void dma16(const u16* g, u16* l) {
    __builtin_amdgcn_global_load_lds(
        (const __attribute__((address_space(1))) u32*)g,
        (__attribute__((address_space(3))) u32*)l, 16, 0, 0);
}

// --- xcvt: X fp32 -> bf16 proj-image ----------------------------------------
// grid 3072 = p*1024 + mtile*16 + kslab ; 128x32 slab per block
__global__ __launch_bounds__(256) void xcvt_kernel(
    const float* __restrict__ xq, const float* __restrict__ xk,
    const float* __restrict__ xv, u16* __restrict__ xb)
{
    const int id = blockIdx.x;
    const int p = id >> 10, rest = id & 1023;
    const int mtile = rest >> 4, kk = rest & 15;
    const float* X = (p == 0) ? xq : ((p == 1) ? xk : xv);
    const int t = threadIdx.x;
    const int row = t >> 1, half = t & 1;
    const float* src = X + ((size_t)(mtile * 128 + row)) * DIM + kk * 32 + half * 16;
    u16* dst = xb + (size_t)p * XSZ + ((size_t)(mtile * 16 + kk)) * 4096 + row * 32;
    const int sr = (row ^ (row >> 2)) & 3;
    float4 a0 = ((const float4*)src)[0], a1 = ((const float4*)src)[1];
    float4 a2 = ((const float4*)src)[2], a3 = ((const float4*)src)[3];
    const int c0 = (half * 2) ^ sr, c1 = (half * 2 + 1) ^ sr;
    *(bf16x8*)(dst + (c0 << 3)) = cvt8p(a0, a1);
    *(bf16x8*)(dst + (c1 << 3)) = cvt8p(a2, a3);
}

// --- wt: W^T bf16 proj-image ------------------------------------------------
__global__ __launch_bounds__(256) void wt_kernel(
    const float* __restrict__ Wq, const float* __restrict__ Wk,
    const float* __restrict__ Wv, u16* __restrict__ wtImg)
{
    __shared__ u16 lT[64 * 65];
    const int p = blockIdx.z;
    const float* W = (p == 0) ? Wq : ((p == 1) ? Wk : Wv);
    const int r0 = blockIdx.x * 64, c0 = blockIdx.y * 64;   // r0 = k, c0 = n
    const int t = threadIdx.x;
#pragma unroll
    for (int i = 0; i < 16; i++) {
        int idx = i * 256 + t, rowk = idx >> 6, coln = idx & 63;
        lT[coln * 65 + rowk] = f2bf(W[(size_t)(r0 + rowk) * DIM + c0 + coln]);
    }
    __syncthreads();
#pragma unroll
    for (int i = 0; i < 2; i++) {
        const int idx = i * 256 + t;           // 0..511
        const int nl = idx >> 3, ch = idx & 7;
        const int n = c0 + nl;
        const int row = n & 127, ntile = n >> 7;
        const int kk = (r0 >> 5) + (ch >> 2);
        const int sw = (ch & 3) ^ ((row ^ (row >> 2)) & 3);
        u16* d = wtImg + (size_t)p * WSZ + ((size_t)(ntile * 16 + kk)) * 4096
               + row * 32 + (sw << 3);
#pragma unroll
        for (int e = 0; e < 8; e++) d[e] = lT[nl * 65 + ch * 8 + e];
    }
}

// --- proj: all-bf16, DMA-staged, XCD-pinned ---------------------------------
__global__ __launch_bounds__(256) void proj_kernel(
    const u16* __restrict__ xb, const u16* __restrict__ wtImg,
    const float* __restrict__ bq, const float* __restrict__ bk,
    const float* __restrict__ bv,
    u16* __restrict__ qb, u16* __restrict__ kbImg, u16* __restrict__ vtImg)
{
    __shared__ u16 smem[16384];   // 2 x (A 4096 | B 4096); epilogue: 128x128 tile

    const int tid = threadIdx.x;
    const int wave = tid >> 6, lane = tid & 63;
    const int l16 = lane & 15, quad = lane >> 4;
    const int wq = wave >> 1, wn = wave & 1;

    // XCD pinning: id&7 = xcd; 96 blocks per XCD (32 per p)
    const int id = blockIdx.x;
    const int xcd = id & 7, j = id >> 3;
    const int p = j >> 5, t5 = j & 31;
    int mb, nb;
    if (p < 2) { mb = xcd * 8 + (t5 >> 2); nb = t5 & 3; }
    else       { nb = xcd * 8 + (t5 >> 2); mb = t5 & 3; }

    const u16* Abase = (p < 2) ? xb + (size_t)p * XSZ + (size_t)mb * 16 * 4096
                               : wtImg + (size_t)2 * WSZ + (size_t)mb * 16 * 4096;
    const u16* Bbase = (p < 2) ? wtImg + (size_t)p * WSZ + (size_t)nb * 16 * 4096
                               : xb + (size_t)2 * XSZ + (size_t)nb * 16 * 4096;
    const int doff = tid * 8;   // u16 units; 16B per thread per dma

    f32x4 acc[4][4];
#pragma unroll
    for (int ms = 0; ms < 4; ms++)
#pragma unroll
        for (int ns = 0; ns < 4; ns++)
#pragma unroll
            for (int jj = 0; jj < 4; jj++) acc[ms][ns][jj] = 0.f;

    // prologue: slab 0 -> buf 0
#pragma unroll
    for (int e = 0; e < 2; e++) {
        dma16(Abase + e * 2048 + doff, smem + e * 2048 + doff);
        dma16(Bbase + e * 2048 + doff, smem + 4096 + e * 2048 + doff);
    }
    Abase += 4096; Bbase += 4096;

    for (int kt = 0; kt < 16; kt++) {
        __syncthreads();
        if (kt < 15) {
            u16* lb = smem + ((kt + 1) & 1) * 8192;
#pragma unroll
            for (int e = 0; e < 2; e++) {
                dma16(Abase + e * 2048 + doff, lb + e * 2048 + doff);
                dma16(Bbase + e * 2048 + doff, lb + 4096 + e * 2048 + doff);
            }
            Abase += 4096; Bbase += 4096;
        }
        const u16* lA = smem + (kt & 1) * 8192;
        const u16* lB = lA + 4096;

        bf16x8 af[4];
#pragma unroll
        for (int ms = 0; ms < 4; ms++) {
            const int row = wq * 64 + ms * 16 + l16;
            const int sr = (row ^ (row >> 2)) & 3;
            af[ms] = *(const bf16x8*)&lA[row * 32 + ((quad ^ sr) << 3)];
        }
#pragma unroll
        for (int ns = 0; ns < 4; ns++) {
            const int rowb = wn * 64 + ns * 16 + l16;
            const int sb = (rowb ^ (rowb >> 2)) & 3;
            const bf16x8 b = *(const bf16x8*)&lB[rowb * 32 + ((quad ^ sb) << 3)];
#pragma unroll
            for (int ms = 0; ms < 4; ms++)
                acc[ms][ns] = __builtin_amdgcn_mfma_f32_16x16x32_bf16(af[ms], b, acc[ms][ns], 0, 0, 0);
        }
    }

    // ---- epilogue: stage tile in LDS in output-image order, dump linearly ---
    __syncthreads();
    if (p < 2) {
        const float* bias = p ? bk : bq;
        const float cs = (p == 0) ? 0.18033688011112042f : 1.0f;   // log2e/8
        const int stl = wn * 2 + wq;
        const int hh = nb * 2 + wn;
#pragma unroll
        for (int ns = 0; ns < 4; ns++) {
            const int ch = ns * 16 + l16;
            const float bval = bias[hh * 64 + ch];
#pragma unroll
            for (int ms = 0; ms < 4; ms++)
#pragma unroll
                for (int rr = 0; rr < 4; rr++) {
                    const int sqL = ms * 16 + quad * 4 + rr;
                    const float v = (acc[ms][ns][rr] + bval) * cs;
                    int off;
                    if (p == 0) off = sqL * 64 + ch;
                    else        off = sqL * 64 +
                                      (((ch >> 3) ^ ((sqL ^ (sqL >> 3)) & 7)) << 3) + (ch & 7);
                    smem[stl * 4096 + off] = f2bf(v);
                }
        }
    } else {
        const int stl = wq * 2 + wn;
#pragma unroll
        for (int ms = 0; ms < 4; ms++)
#pragma unroll
            for (int rr = 0; rr < 4; rr++) {
                const int hd = ms * 16 + quad * 4 + rr;
                const float bval = bv[mb * 128 + wq * 64 + hd];
                const int swh = (hd ^ (hd >> 3)) & 7;
#pragma unroll
                for (int ns = 0; ns < 4; ns++) {
                    const int nl = ns * 16 + l16;
                    const int sqpL = (nl & ~12) | ((nl & 8) >> 1) | ((nl & 4) << 1);
                    smem[stl * 4096 + hd * 64 +
                         (((sqpL >> 3) ^ swh) << 3) + (sqpL & 7)] =
                        f2h(acc[ms][ns][rr] + bval);
                }
            }
    }
    __syncthreads();

    {
        u16* dstp; size_t gbase;
        if (p < 2) {
            const int hh = nb * 2 + (wave >> 1);
            const int b2 = mb >> 5;
            const int row0 = (mb * 128 + (wave & 1) * 64) & 4095;
            if (p == 0) { dstp = qb;    gbase = ((size_t)(b2 * NH + hh) * 4096 + row0) * 64; }
            else        { dstp = kbImg; gbase = ((size_t)((b2 * NH + hh) * 64 + (row0 >> 6))) * 4096; }
        } else {
            const int hh = mb * 2 + (wave >> 1);
            const int b2 = nb >> 5;
            const int nblk = (nb & 31) * 2 + (wave & 1);
            dstp = vtImg; gbase = ((size_t)((b2 * NH + hh) * 64 + nblk)) * 4096;
        }
#pragma unroll
        for (int e = 0; e < 8; e++) {
            const u32x4 vv = *(const u32x4*)&smem[wave * 4096 + e * 512 + lane * 8];
            *(u32x4*)(dstp + gbase + e * 512 + lane * 8) = vv;
        }
    }
}

// --- flash attention: 512 threads, 4 wq x 2 kh, DMA double-buffer ------------
__global__ __launch_bounds__(512, 4) void attn_kernel(
    const u16* __restrict__ qb, const u16* __restrict__ kbImg,
    const u16* __restrict__ vtImg, float* __restrict__ out)
{
    __shared__ u16 smem[2 * 4 * 4096];   // [buf][kh*2+kv][8KB] = 64KB
    float* cmb = (float*)smem;

    const int tid = threadIdx.x;
    const int wave = tid >> 6, lane = tid & 63;
    const int m31 = lane & 31, h = lane >> 5;
    const int wq = wave >> 1, kh = wave & 1;

    const int blk = blockIdx.x;
    const int xcd = blk & 7, idx = blk >> 3;
    const int bh = xcd * 2 + (idx >> 5);
    const int qt = idx & 31;
    const int qbase = qt * 128 + wq * 32;

    bf16x8 qF[4];
#pragma unroll
    for (int c = 0; c < 4; c++)
        qF[c] = *(const bf16x8*)(qb + ((size_t)bh * SEQ + qbase + m31) * HD + c * 16 + h * 8);

    f32x16 O0, O1;
#pragma unroll
    for (int j = 0; j < 16; j++) { O0[j] = 0.f; O1[j] = 0.f; }
    float l_acc = 0.f;

    const int st  = wave >> 1;
    const int hw  = wave & 1;
    const u16* img = (st & 1) ? vtImg : kbImg;
    const u16* gp = img + ((size_t)(bh * 64 + (st >> 1) * 32)) * 4096 + hw * 2048 + lane * 8;
    {
        u16* lb = smem + st * 4096 + hw * 2048 + lane * 8;
#pragma unroll
        for (int e = 0; e < 4; e++) dma16(gp + e * 512, lb + e * 512);
        gp += 4096;
    }

    const int NT = 32;
    for (int it = 0; it < NT; it++) {
        __syncthreads();
        if (it + 1 < NT) {
            u16* lb = smem + ((((it + 1) & 1) * 4 + st)) * 4096 + hw * 2048 + lane * 8;
#pragma unroll
            for (int e = 0; e < 4; e++) dma16(gp + e * 512, lb + e * 512);
            gp += 4096;
        }
        const u16* sK = smem + (size_t)(((it & 1) * 4) + kh * 2) * 4096;
        const u16* sV = sK + 4096;

#pragma unroll
        for (int kg = 0; kg < 2; kg++) {
            const int rK = kg * 32 + m31;
            const int swK = (rK ^ (rK >> 3)) & 7;
            bf16x8 kA[4];
#pragma unroll
            for (int c = 0; c < 4; c++)
                kA[c] = *(const bf16x8*)&sK[(rK << 6) + (((2 * c + h) ^ swK) << 3)];

            const int swV0 = (m31 ^ (m31 >> 3)) & 7;
            const int rV1 = 32 + m31;
            const int swV1 = (rV1 ^ (rV1 >> 3)) & 7;
            f16x8 vA0[2], vA1[2];
#pragma unroll
            for (int c2 = 0; c2 < 2; c2++) {
                vA0[c2] = *(const f16x8*)&sV[(m31 << 6) + (((4 * kg + 2 * c2 + h) ^ swV0) << 3)];
                vA1[c2] = *(const f16x8*)&sV[(rV1 << 6) + (((4 * kg + 2 * c2 + h) ^ swV1) << 3)];
            }

            f32x16 Sv;
#pragma unroll
            for (int j = 0; j < 16; j++) Sv[j] = 0.f;
#pragma unroll
            for (int c = 0; c < 4; c++)
                Sv = __builtin_amdgcn_mfma_f32_32x32x16_bf16(kA[c], qF[c], Sv, 0, 0, 0);

            float ps = 0.f;
            u32 P32[8];
#pragma unroll
            for (int mm = 0; mm < 8; mm++) {
                const float e0 = __builtin_amdgcn_exp2f(Sv[2 * mm]);
                const float e1 = __builtin_amdgcn_exp2f(Sv[2 * mm + 1]);
                ps += e0 + e1;
                P32[mm] = pack_pkrtz(e0, e1);
            }
            l_acc += ps;

            u32x4 f0, f1;
            f0[0] = P32[0]; f0[1] = P32[1]; f0[2] = P32[2]; f0[3] = P32[3];
            f1[0] = P32[4]; f1[1] = P32[5]; f1[2] = P32[6]; f1[3] = P32[7];
            const f16x8 pf0 = __builtin_bit_cast(f16x8, f0);
            const f16x8 pf1 = __builtin_bit_cast(f16x8, f1);
            O0 = __builtin_amdgcn_mfma_f32_32x32x16_f16(vA0[0], pf0, O0, 0, 0, 0);
            O0 = __builtin_amdgcn_mfma_f32_32x32x16_f16(vA0[1], pf1, O0, 0, 0, 0);
            O1 = __builtin_amdgcn_mfma_f32_32x32x16_f16(vA1[0], pf0, O1, 0, 0, 0);
            O1 = __builtin_amdgcn_mfma_f32_32x32x16_f16(vA1[1], pf1, O1, 0, 0, 0);
        }
    }

    l_acc += __shfl_xor(l_acc, 32);
    __syncthreads();
    if (kh == 1) {
#pragma unroll
        for (int hg = 0; hg < 2; hg++)
#pragma unroll
            for (int mm = 0; mm < 4; mm++) {
                f32x4 o;
#pragma unroll
                for (int j = 0; j < 4; j++) o[j] = (hg ? O1 : O0)[4 * mm + j];
                *(f32x4*)&cmb[(((wq * 2 + hg) * 4 + mm) << 8) + lane * 4] = o;
            }
        cmb[8192 + wq * 64 + lane] = l_acc;
    }
    __syncthreads();

    if (kh == 0) {
        const int b = bh >> 3, hcol = bh & 7;
        const float lt = l_acc + cmb[8192 + wq * 64 + lane];
        const float inv = 1.0f / lt;
        const int sq = qbase + m31;
#pragma unroll
        for (int hg = 0; hg < 2; hg++)
#pragma unroll
            for (int mm = 0; mm < 4; mm++) {
                const f32x4 po = *(const f32x4*)&cmb[(((wq * 2 + hg) * 4 + mm) << 8) + lane * 4];
                f32x4 o;
#pragma unroll
                for (int j = 0; j < 4; j++)
                    o[j] = ((hg ? O1 : O0)[4 * mm + j] + po[j]) * inv;
                *(f32x4*)&out[(((size_t)(b * SEQ + sq)) << 9) + hcol * 64
                              + hg * 32 + 8 * mm + 4 * h] = o;
            }
    }
}

// ---------------------------------------------------------------------------
extern "C" void kernel_launch(void* const* d_in, const int* in_sizes, int n_in,
                              void* d_out, int out_size, void* d_ws, size_t ws_size,
                              hipStream_t stream)
{
    const float* q  = (const float*)d_in[0];
    const float* k  = (const float*)d_in[1];
    const float* v  = (const float*)d_in[2];
    const float* Wq = (const float*)d_in[3];
    const float* bq = (const float*)d_in[4];
    const float* Wk = (const float*)d_in[5];
    const float* bk = (const float*)d_in[6];
    const float* Wv = (const float*)d_in[7];
    const float* bv = (const float*)d_in[8];
    float* out = (float*)d_out;

    // ws layout (u16): xb[3*XSZ] | wtImg[3*WSZ] | qb[QSZ] | kbImg[QSZ] | vtImg[QSZ]
    u16* xb  = (u16*)d_ws;
    u16* wti = xb  + (size_t)3 * XSZ;
    u16* qbp = wti + (size_t)3 * WSZ;
    u16* kbp = qbp + (size_t)QSZ;
    u16* vtp = kbp + (size_t)QSZ;

    xcvt_kernel<<<dim3(3072),   256, 0, stream>>>(q, k, v, xb);
    wt_kernel  <<<dim3(8, 8, 3), 256, 0, stream>>>(Wq, Wk, Wv, wti);
    proj_kernel<<<dim3(768),    256, 0, stream>>>(xb, wti, bq, bk, bv,
                                                  qbp, kbp, vtp);
    attn_kernel<<<dim3(512),    512, 0, stream>>>(qbp, kbp, vtp, out);
}